// Round 1
// baseline (2548.270 us; speedup 1.0000x reference)
//
#include <hip/hip_runtime.h>
#include <hip/hip_bf16.h>
#include <math.h>

// Problem constants (B=4, C=1024, d=1024)
#define T_TOK 4096
#define D     1024
#define DFF   4096
#define NEXP  8
#define CAP   1280   // floor(2*1.25*4096/8)=1280, already even
#define TOPK  2

// ---------------------------------------------------------------------------
// Router: logits = x @ w_g, top-2 (lowest-index tie-break like lax.top_k),
// softmax over the two kept logits. One wave (64 lanes) per token.
// ---------------------------------------------------------------------------
__global__ __launch_bounds__(256) void router_kernel(
    const float* __restrict__ x, const float* __restrict__ wg,
    int* __restrict__ top_e, float* __restrict__ top_p) {
  int t = blockIdx.x * 4 + (threadIdx.x >> 6);
  int lane = threadIdx.x & 63;
  if (t >= T_TOK) return;
  const float* xr = x + (size_t)t * D;
  float acc[NEXP];
#pragma unroll
  for (int e = 0; e < NEXP; e++) acc[e] = 0.f;
  for (int dd = lane; dd < D; dd += 64) {
    float xv = xr[dd];
    const float* wr = wg + dd * NEXP;
#pragma unroll
    for (int e = 0; e < NEXP; e++) acc[e] += xv * wr[e];
  }
#pragma unroll
  for (int off = 32; off > 0; off >>= 1) {
#pragma unroll
    for (int e = 0; e < NEXP; e++) acc[e] += __shfl_xor(acc[e], off, 64);
  }
  if (lane == 0) {
    int b0 = 0; float v0 = acc[0];
    for (int e = 1; e < NEXP; e++) if (acc[e] > v0) { v0 = acc[e]; b0 = e; }
    int b1 = -1; float v1 = -INFINITY;
    for (int e = 0; e < NEXP; e++) if (e != b0 && acc[e] > v1) { v1 = acc[e]; b1 = e; }
    // v0 >= v1; softmax over the two kept entries (others are -inf -> 0)
    float e0 = 1.0f;              // exp(v0 - v0)
    float e1 = expf(v1 - v0);
    float s = e0 + e1;
    top_e[t * 2 + 0] = b0; top_e[t * 2 + 1] = b1;
    top_p[t * 2 + 0] = e0 / s; top_p[t * 2 + 1] = e1 / s;
  }
}

// ---------------------------------------------------------------------------
// Rank/capacity: exact nanoMoE cumsum semantics. Flattened order is
// [k=0: tokens 0..T) then [k=1: tokens 0..T). rank(k,t,e) = #prior
// assignments to e in that order; drop if rank >= CAP.
// Single block of 1024 threads, 4 tokens/thread, 8-vector inclusive scan.
// ---------------------------------------------------------------------------
__global__ __launch_bounds__(1024) void rank_kernel(
    const int* __restrict__ top_e, const float* __restrict__ top_p,
    int* __restrict__ slot_token, int* __restrict__ tok_slot,
    float* __restrict__ tok_w) {
  __shared__ int sc[1024][9];  // padded to kill stride-8 bank conflicts
  int tid = threadIdx.x;
  int base[NEXP];
#pragma unroll
  for (int e = 0; e < NEXP; e++) base[e] = 0;

  for (int k = 0; k < TOPK; k++) {
    int cnt[NEXP];
#pragma unroll
    for (int e = 0; e < NEXP; e++) cnt[e] = 0;
    int eloc[4];
#pragma unroll
    for (int i = 0; i < 4; i++) {
      int t = tid * 4 + i;
      int e = top_e[t * 2 + k];
      eloc[i] = e;
#pragma unroll
      for (int q = 0; q < NEXP; q++) cnt[q] += (q == e);
    }
    __syncthreads();  // protect sc from previous iteration's readers
#pragma unroll
    for (int e = 0; e < NEXP; e++) sc[tid][e] = cnt[e];
    __syncthreads();
    // Hillis-Steele inclusive scan over 1024 threads, 8-wide vector
    for (int off = 1; off < 1024; off <<= 1) {
      int v[NEXP];
#pragma unroll
      for (int e = 0; e < NEXP; e++) v[e] = (tid >= off) ? sc[tid - off][e] : 0;
      __syncthreads();
#pragma unroll
      for (int e = 0; e < NEXP; e++) sc[tid][e] += v[e];
      __syncthreads();
    }
    int excl[NEXP];
#pragma unroll
    for (int e = 0; e < NEXP; e++) excl[e] = sc[tid][e] - cnt[e] + base[e];
    int nbase[NEXP];
#pragma unroll
    for (int e = 0; e < NEXP; e++) nbase[e] = base[e] + sc[1023][e];  // totals

    int run[NEXP];
#pragma unroll
    for (int e = 0; e < NEXP; e++) run[e] = 0;
#pragma unroll
    for (int i = 0; i < 4; i++) {
      int t = tid * 4 + i;
      int e = eloc[i];
      int r = 0;
#pragma unroll
      for (int q = 0; q < NEXP; q++)
        if (q == e) { r = excl[q] + run[q]; run[q]++; }
      if (r < CAP) {
        slot_token[e * CAP + r] = t;
        tok_slot[t * 2 + k] = e * CAP + r;
      } else {
        tok_slot[t * 2 + k] = -1;
      }
      tok_w[t * 2 + k] = top_p[t * 2 + k];
    }
#pragma unroll
    for (int e = 0; e < NEXP; e++) base[e] = nbase[e];
  }
}

// ---------------------------------------------------------------------------
// Dispatch gather: xb[e,c,:] = x[slot_token[e*CAP+c],:] or 0 if unfilled.
// One block per slot, float4 copies.
// ---------------------------------------------------------------------------
__global__ __launch_bounds__(256) void gather_kernel(
    const float* __restrict__ x, const int* __restrict__ slot_token,
    float* __restrict__ xb) {
  int slot = blockIdx.x;
  int tok = slot_token[slot];
  int i = threadIdx.x;  // 256 float4 = 1024 floats
  float4 v = make_float4(0.f, 0.f, 0.f, 0.f);
  if (tok >= 0) v = ((const float4*)(x + (size_t)tok * D))[i];
  ((float4*)(xb + (size_t)slot * D))[i] = v;
}

// ---------------------------------------------------------------------------
// fp32 tiled GEMM: C[e] = A[e] (MxK) @ B[e] (KxN), optional exact GELU.
// 64x64 block tile, 16 K-step, 256 threads, 4x4 per thread.
// All dims divisible by tile sizes (M=1280, N in {4096,1024}, K in {1024,4096}).
// ---------------------------------------------------------------------------
template <bool GELU>
__global__ __launch_bounds__(256) void gemm_kernel(
    const float* __restrict__ A, const float* __restrict__ B,
    float* __restrict__ C, int M, int N, int K) {
  __shared__ float As[16][65];  // [k][m], padded
  __shared__ float Bs[16][64];  // [k][n]
  int e = blockIdx.z;
  A += (size_t)e * M * K;
  B += (size_t)e * K * N;
  C += (size_t)e * M * N;
  int tid = threadIdx.x;
  int tx = tid & 15, ty = tid >> 4;
  int row0 = blockIdx.y * 64, col0 = blockIdx.x * 64;
  float acc[4][4] = {};

  int a_row = tid >> 2;         // 0..63
  int a_k4 = (tid & 3) * 4;     // 0,4,8,12
  int b_row = tid >> 4;         // 0..15
  int b_col = (tid & 15) * 4;   // 0..60

  for (int k0 = 0; k0 < K; k0 += 16) {
    float4 av = *(const float4*)(A + (size_t)(row0 + a_row) * K + k0 + a_k4);
    float4 bv = *(const float4*)(B + (size_t)(k0 + b_row) * N + col0 + b_col);
    As[a_k4 + 0][a_row] = av.x;
    As[a_k4 + 1][a_row] = av.y;
    As[a_k4 + 2][a_row] = av.z;
    As[a_k4 + 3][a_row] = av.w;
    *(float4*)&Bs[b_row][b_col] = bv;
    __syncthreads();
#pragma unroll
    for (int kk = 0; kk < 16; kk++) {
      float a0 = As[kk][ty * 4 + 0];
      float a1 = As[kk][ty * 4 + 1];
      float a2 = As[kk][ty * 4 + 2];
      float a3 = As[kk][ty * 4 + 3];
      float4 b = *(float4*)&Bs[kk][tx * 4];
      acc[0][0] += a0 * b.x; acc[0][1] += a0 * b.y; acc[0][2] += a0 * b.z; acc[0][3] += a0 * b.w;
      acc[1][0] += a1 * b.x; acc[1][1] += a1 * b.y; acc[1][2] += a1 * b.z; acc[1][3] += a1 * b.w;
      acc[2][0] += a2 * b.x; acc[2][1] += a2 * b.y; acc[2][2] += a2 * b.z; acc[2][3] += a2 * b.w;
      acc[3][0] += a3 * b.x; acc[3][1] += a3 * b.y; acc[3][2] += a3 * b.z; acc[3][3] += a3 * b.w;
    }
    __syncthreads();
  }

#pragma unroll
  for (int i = 0; i < 4; i++) {
    float4 o;
    float* oo = (float*)&o;
#pragma unroll
    for (int j = 0; j < 4; j++) {
      float v = acc[i][j];
      if (GELU) v = 0.5f * v * (1.f + erff(v * 0.70710678118654752f));
      oo[j] = v;
    }
    *(float4*)(C + (size_t)(row0 + ty * 4 + i) * N + col0 + tx * 4) = o;
  }
}

// ---------------------------------------------------------------------------
// Combine: out[t,:] = sum_k kept(w_k * exp_out[slot_k,:]). One block per token.
// ---------------------------------------------------------------------------
__global__ __launch_bounds__(256) void combine_kernel(
    const float* __restrict__ eo, const int* __restrict__ tok_slot,
    const float* __restrict__ tok_w, float* __restrict__ out) {
  int t = blockIdx.x;
  int i = threadIdx.x;
  float4 acc = make_float4(0.f, 0.f, 0.f, 0.f);
#pragma unroll
  for (int k = 0; k < TOPK; k++) {
    int s = tok_slot[t * 2 + k];
    if (s >= 0) {
      float w = tok_w[t * 2 + k];
      float4 v = ((const float4*)(eo + (size_t)s * D))[i];
      acc.x += w * v.x; acc.y += w * v.y; acc.z += w * v.z; acc.w += w * v.w;
    }
  }
  ((float4*)(out + (size_t)t * D))[i] = acc;
}

// ---------------------------------------------------------------------------
extern "C" void kernel_launch(void* const* d_in, const int* in_sizes, int n_in,
                              void* d_out, int out_size, void* d_ws, size_t ws_size,
                              hipStream_t stream) {
  const float* x     = (const float*)d_in[0];  // [4,1024,1024]
  const float* wg    = (const float*)d_in[1];  // [1024,8]
  const float* cfc   = (const float*)d_in[2];  // [8,1024,4096]
  const float* cproj = (const float*)d_in[3];  // [8,4096,1024]
  float* out = (float*)d_out;

  char* ws = (char*)d_ws;
  size_t off = 0;
  auto alloc = [&](size_t bytes) -> void* {
    void* p = ws + off;
    off += (bytes + 255) & ~(size_t)255;
    return p;
  };
  int*   top_e      = (int*)  alloc((size_t)T_TOK * 2 * 4);
  float* top_p      = (float*)alloc((size_t)T_TOK * 2 * 4);
  int*   slot_token = (int*)  alloc((size_t)NEXP * CAP * 4);
  int*   tok_slot   = (int*)  alloc((size_t)T_TOK * 2 * 4);
  float* tok_w      = (float*)alloc((size_t)T_TOK * 2 * 4);
  float* xb         = (float*)alloc((size_t)NEXP * CAP * D * 4);
  float* h          = (float*)alloc((size_t)NEXP * CAP * DFF * 4);
  float* eo         = (float*)alloc((size_t)NEXP * CAP * D * 4);

  hipMemsetAsync(slot_token, 0xFF, (size_t)NEXP * CAP * 4, stream);  // -1 = empty
  router_kernel<<<T_TOK / 4, 256, 0, stream>>>(x, wg, top_e, top_p);
  rank_kernel<<<1, 1024, 0, stream>>>(top_e, top_p, slot_token, tok_slot, tok_w);
  gather_kernel<<<NEXP * CAP, 256, 0, stream>>>(x, slot_token, xb);
  gemm_kernel<true><<<dim3(DFF / 64, CAP / 64, NEXP), 256, 0, stream>>>(
      xb, cfc, h, CAP, DFF, D);
  gemm_kernel<false><<<dim3(D / 64, CAP / 64, NEXP), 256, 0, stream>>>(
      h, cproj, eo, CAP, D, DFF);
  combine_kernel<<<T_TOK, 256, 0, stream>>>(eo, tok_slot, tok_w, out);
}

// Round 2
// 670.832 us; speedup vs baseline: 3.7987x; 3.7987x over previous
//
#include <hip/hip_runtime.h>
#include <hip/hip_bf16.h>
#include <math.h>

// Problem constants (B=4, C=1024, d=1024)
#define T_TOK 4096
#define D     1024
#define DFF   4096
#define NEXP  8
#define CAP   1280   // floor(2*1.25*4096/8)=1280, already even
#define TOPK  2

typedef __bf16 bf16x8 __attribute__((ext_vector_type(8)));
typedef float floatx4 __attribute__((ext_vector_type(4)));

__device__ __forceinline__ unsigned short f2bf(float f) {
  union { float f; unsigned u; } un; un.f = f;
  unsigned r = un.u + 0x7FFF + ((un.u >> 16) & 1);  // RNE
  return (unsigned short)(r >> 16);
}

// ---------------------------------------------------------------------------
// Router: logits = x @ w_g, top-2 (lowest-index tie-break like lax.top_k),
// softmax over the two kept logits. One wave per token. (unchanged, verified)
// ---------------------------------------------------------------------------
__global__ __launch_bounds__(256) void router_kernel(
    const float* __restrict__ x, const float* __restrict__ wg,
    int* __restrict__ top_e, float* __restrict__ top_p) {
  int t = blockIdx.x * 4 + (threadIdx.x >> 6);
  int lane = threadIdx.x & 63;
  if (t >= T_TOK) return;
  const float* xr = x + (size_t)t * D;
  float acc[NEXP];
#pragma unroll
  for (int e = 0; e < NEXP; e++) acc[e] = 0.f;
  for (int dd = lane; dd < D; dd += 64) {
    float xv = xr[dd];
    const float* wr = wg + dd * NEXP;
#pragma unroll
    for (int e = 0; e < NEXP; e++) acc[e] += xv * wr[e];
  }
#pragma unroll
  for (int off = 32; off > 0; off >>= 1) {
#pragma unroll
    for (int e = 0; e < NEXP; e++) acc[e] += __shfl_xor(acc[e], off, 64);
  }
  if (lane == 0) {
    int b0 = 0; float v0 = acc[0];
    for (int e = 1; e < NEXP; e++) if (acc[e] > v0) { v0 = acc[e]; b0 = e; }
    int b1 = -1; float v1 = -INFINITY;
    for (int e = 0; e < NEXP; e++) if (e != b0 && acc[e] > v1) { v1 = acc[e]; b1 = e; }
    float e1 = expf(v1 - v0);
    float s = 1.0f + e1;
    top_e[t * 2 + 0] = b0; top_e[t * 2 + 1] = b1;
    top_p[t * 2 + 0] = 1.0f / s; top_p[t * 2 + 1] = e1 / s;
  }
}

// ---------------------------------------------------------------------------
// Rank/capacity: exact nanoMoE cumsum semantics (unchanged, verified).
// ---------------------------------------------------------------------------
__global__ __launch_bounds__(1024) void rank_kernel(
    const int* __restrict__ top_e, const float* __restrict__ top_p,
    int* __restrict__ slot_token, int* __restrict__ tok_slot,
    float* __restrict__ tok_w) {
  __shared__ int sc[1024][9];
  int tid = threadIdx.x;
  int base[NEXP];
#pragma unroll
  for (int e = 0; e < NEXP; e++) base[e] = 0;

  for (int k = 0; k < TOPK; k++) {
    int cnt[NEXP];
#pragma unroll
    for (int e = 0; e < NEXP; e++) cnt[e] = 0;
    int eloc[4];
#pragma unroll
    for (int i = 0; i < 4; i++) {
      int t = tid * 4 + i;
      int e = top_e[t * 2 + k];
      eloc[i] = e;
#pragma unroll
      for (int q = 0; q < NEXP; q++) cnt[q] += (q == e);
    }
    __syncthreads();
#pragma unroll
    for (int e = 0; e < NEXP; e++) sc[tid][e] = cnt[e];
    __syncthreads();
    for (int off = 1; off < 1024; off <<= 1) {
      int v[NEXP];
#pragma unroll
      for (int e = 0; e < NEXP; e++) v[e] = (tid >= off) ? sc[tid - off][e] : 0;
      __syncthreads();
#pragma unroll
      for (int e = 0; e < NEXP; e++) sc[tid][e] += v[e];
      __syncthreads();
    }
    int excl[NEXP];
#pragma unroll
    for (int e = 0; e < NEXP; e++) excl[e] = sc[tid][e] - cnt[e] + base[e];
    int nbase[NEXP];
#pragma unroll
    for (int e = 0; e < NEXP; e++) nbase[e] = base[e] + sc[1023][e];

    int run[NEXP];
#pragma unroll
    for (int e = 0; e < NEXP; e++) run[e] = 0;
#pragma unroll
    for (int i = 0; i < 4; i++) {
      int t = tid * 4 + i;
      int e = eloc[i];
      int r = 0;
#pragma unroll
      for (int q = 0; q < NEXP; q++)
        if (q == e) { r = excl[q] + run[q]; run[q]++; }
      if (r < CAP) {
        slot_token[e * CAP + r] = t;
        tok_slot[t * 2 + k] = e * CAP + r;
      } else {
        tok_slot[t * 2 + k] = -1;
      }
      tok_w[t * 2 + k] = top_p[t * 2 + k];
    }
#pragma unroll
    for (int e = 0; e < NEXP; e++) base[e] = nbase[e];
  }
}

// ---------------------------------------------------------------------------
// Gather + fp32->bf16: xb[slot,:] = bf16(x[token,:]) or 0.
// ---------------------------------------------------------------------------
__global__ __launch_bounds__(256) void gather_cvt_kernel(
    const float* __restrict__ x, const int* __restrict__ slot_token,
    unsigned short* __restrict__ xb) {
  int slot = blockIdx.x;
  int tok = slot_token[slot];
  int i = threadIdx.x;  // 256 x 4 floats = 1024
  float4 v = make_float4(0.f, 0.f, 0.f, 0.f);
  if (tok >= 0) v = ((const float4*)(x + (size_t)tok * D))[i];
  ushort4 o;
  o.x = f2bf(v.x); o.y = f2bf(v.y); o.z = f2bf(v.z); o.w = f2bf(v.w);
  ((ushort4*)(xb + (size_t)slot * D))[i] = o;
}

// ---------------------------------------------------------------------------
// Transpose + fp32->bf16: src [E][R][Cc] row-major -> dst [E][Cc][R] bf16.
// 32x32 LDS tile, 256 threads.
// ---------------------------------------------------------------------------
__global__ __launch_bounds__(256) void transpose_cvt_kernel(
    const float* __restrict__ src, unsigned short* __restrict__ dst,
    int R, int Cc) {
  __shared__ float tile[32][33];
  int e = blockIdx.z;
  src += (size_t)e * R * Cc;
  dst += (size_t)e * R * Cc;
  int r0 = blockIdx.y * 32, c0 = blockIdx.x * 32;
  int tx = threadIdx.x & 31, ty = threadIdx.x >> 5;  // ty 0..7
#pragma unroll
  for (int i = 0; i < 32; i += 8)
    tile[ty + i][tx] = src[(size_t)(r0 + ty + i) * Cc + c0 + tx];
  __syncthreads();
#pragma unroll
  for (int i = 0; i < 32; i += 8)
    dst[(size_t)(c0 + ty + i) * R + r0 + tx] = f2bf(tile[tx][ty + i]);
}

// ---------------------------------------------------------------------------
// bf16 MFMA GEMM (m97 structure): C[e] = A[e] (MxK) @ Bt[e] (NxK)^T.
// 128x128 tile, BK=32, 256 threads = 4 waves (2x2 of 64x64), 4x4 MFMA tiles
// of 16x16x32 per wave. global_load_lds width=16 staging, 2-barrier K-loop.
// OUT_BF16: store bf16 (with optional exact GELU) else fp32.
// ---------------------------------------------------------------------------
template <bool GELU, bool OUT_BF16>
__global__ __launch_bounds__(256) void gemm_mfma_kernel(
    const unsigned short* __restrict__ A,   // [E][M][K] bf16
    const unsigned short* __restrict__ Bt,  // [E][N][K] bf16
    void* __restrict__ Cv, int M, int N, int K) {
  __shared__ unsigned short As[128 * 32];  // [m][k], 8 KB
  __shared__ unsigned short Bs[128 * 32];  // [n][k], 8 KB

  int e = blockIdx.z;
  A  += (size_t)e * M * K;
  Bt += (size_t)e * N * K;
  int row0 = blockIdx.y * 128, col0 = blockIdx.x * 128;

  int tid = threadIdx.x;
  int wave = tid >> 6, lane = tid & 63;

  // Staging: chunk = 16 rows x 32 k. Wave w stages chunks w and w+4 of A and B.
  // lane i -> row = chunk*16 + i/4, kcol = (i%4)*8; LDS dest = base + 16*i bytes.
  int sr = lane >> 2;            // 0..15
  int sk = (lane & 3) * 8;       // 0,8,16,24
  size_t a_off0 = (size_t)(row0 + wave * 16 + sr) * K + sk;
  size_t a_off1 = a_off0 + (size_t)64 * K;
  size_t b_off0 = (size_t)(col0 + wave * 16 + sr) * K + sk;
  size_t b_off1 = b_off0 + (size_t)64 * K;
  unsigned short* as_dst0 = As + (wave * 16) * 32;
  unsigned short* as_dst1 = As + (wave * 16 + 64) * 32;
  unsigned short* bs_dst0 = Bs + (wave * 16) * 32;
  unsigned short* bs_dst1 = Bs + (wave * 16 + 64) * 32;

  // Compute: wave (2x2), 4x4 tiles of 16x16.
  int wm = (wave >> 1) * 64;
  int wn = (wave & 1) * 64;
  int fr = lane & 15;            // row/col within 16
  int fq = lane >> 4;            // quad: k = fq*8 + j

  floatx4 acc[4][4];
#pragma unroll
  for (int i = 0; i < 4; i++)
#pragma unroll
    for (int j = 0; j < 4; j++) acc[i][j] = (floatx4){0.f, 0.f, 0.f, 0.f};

  for (int k0 = 0; k0 < K; k0 += 32) {
    __builtin_amdgcn_global_load_lds(
        (const __attribute__((address_space(1))) unsigned int*)(A + a_off0 + k0),
        (__attribute__((address_space(3))) unsigned int*)as_dst0, 16, 0, 0);
    __builtin_amdgcn_global_load_lds(
        (const __attribute__((address_space(1))) unsigned int*)(A + a_off1 + k0),
        (__attribute__((address_space(3))) unsigned int*)as_dst1, 16, 0, 0);
    __builtin_amdgcn_global_load_lds(
        (const __attribute__((address_space(1))) unsigned int*)(Bt + b_off0 + k0),
        (__attribute__((address_space(3))) unsigned int*)bs_dst0, 16, 0, 0);
    __builtin_amdgcn_global_load_lds(
        (const __attribute__((address_space(1))) unsigned int*)(Bt + b_off1 + k0),
        (__attribute__((address_space(3))) unsigned int*)bs_dst1, 16, 0, 0);
    __syncthreads();  // drains vmcnt (compiler emits vmcnt(0) before s_barrier)

    bf16x8 af[4], bfr[4];
#pragma unroll
    for (int mi = 0; mi < 4; mi++)
      af[mi] = *(const bf16x8*)&As[(wm + mi * 16 + fr) * 32 + fq * 8];
#pragma unroll
    for (int ni = 0; ni < 4; ni++)
      bfr[ni] = *(const bf16x8*)&Bs[(wn + ni * 16 + fr) * 32 + fq * 8];
#pragma unroll
    for (int mi = 0; mi < 4; mi++)
#pragma unroll
      for (int ni = 0; ni < 4; ni++)
        acc[mi][ni] = __builtin_amdgcn_mfma_f32_16x16x32_bf16(
            af[mi], bfr[ni], acc[mi][ni], 0, 0, 0);
    __syncthreads();  // LDS safe to overwrite next iter
  }

  // Epilogue. C/D layout: col = lane&15, row = (lane>>4)*4 + reg.
  int orow0 = row0 + wm + fq * 4;
  int ocol0 = col0 + wn + fr;
#pragma unroll
  for (int mi = 0; mi < 4; mi++) {
#pragma unroll
    for (int ni = 0; ni < 4; ni++) {
#pragma unroll
      for (int r = 0; r < 4; r++) {
        float v = acc[mi][ni][r];
        if (GELU) v = 0.5f * v * (1.f + erff(v * 0.70710678118654752f));
        size_t idx = (size_t)e * M * N + (size_t)(orow0 + mi * 16 + r) * N +
                     (ocol0 + ni * 16);
        if (OUT_BF16)
          ((unsigned short*)Cv)[idx] = f2bf(v);
        else
          ((float*)Cv)[idx] = v;
      }
    }
  }
}

// ---------------------------------------------------------------------------
// Combine: out[t,:] = sum_k kept(w_k * eo[slot_k,:]). (unchanged, verified)
// ---------------------------------------------------------------------------
__global__ __launch_bounds__(256) void combine_kernel(
    const float* __restrict__ eo, const int* __restrict__ tok_slot,
    const float* __restrict__ tok_w, float* __restrict__ out) {
  int t = blockIdx.x;
  int i = threadIdx.x;
  float4 acc = make_float4(0.f, 0.f, 0.f, 0.f);
#pragma unroll
  for (int k = 0; k < TOPK; k++) {
    int s = tok_slot[t * 2 + k];
    if (s >= 0) {
      float w = tok_w[t * 2 + k];
      float4 v = ((const float4*)(eo + (size_t)s * D))[i];
      acc.x += w * v.x; acc.y += w * v.y; acc.z += w * v.z; acc.w += w * v.w;
    }
  }
  ((float4*)(out + (size_t)t * D))[i] = acc;
}

// ---------------------------------------------------------------------------
extern "C" void kernel_launch(void* const* d_in, const int* in_sizes, int n_in,
                              void* d_out, int out_size, void* d_ws, size_t ws_size,
                              hipStream_t stream) {
  const float* x     = (const float*)d_in[0];  // [4,1024,1024]
  const float* wg    = (const float*)d_in[1];  // [1024,8]
  const float* cfc   = (const float*)d_in[2];  // [8,1024,4096]
  const float* cproj = (const float*)d_in[3];  // [8,4096,1024]
  float* out = (float*)d_out;

  char* ws = (char*)d_ws;
  size_t off = 0;
  auto alloc = [&](size_t bytes) -> void* {
    void* p = ws + off;
    off += (bytes + 255) & ~(size_t)255;
    return p;
  };
  int*   top_e      = (int*)  alloc((size_t)T_TOK * 2 * 4);
  float* top_p      = (float*)alloc((size_t)T_TOK * 2 * 4);
  int*   slot_token = (int*)  alloc((size_t)NEXP * CAP * 4);
  int*   tok_slot   = (int*)  alloc((size_t)T_TOK * 2 * 4);
  float* tok_w      = (float*)alloc((size_t)T_TOK * 2 * 4);
  unsigned short* xb      = (unsigned short*)alloc((size_t)NEXP * CAP * D * 2);   // bf16
  unsigned short* cfc_t   = (unsigned short*)alloc((size_t)NEXP * D * DFF * 2);   // bf16 [e][DFF][D]
  unsigned short* cproj_t = (unsigned short*)alloc((size_t)NEXP * DFF * D * 2);   // bf16 [e][D][DFF]
  unsigned short* h       = (unsigned short*)alloc((size_t)NEXP * CAP * DFF * 2); // bf16
  // eo (fp32, 42 MB) aliases the dead xb+cfc_t region (88 MB) after GEMM1.
  float* eo = (float*)xb;

  hipMemsetAsync(slot_token, 0xFF, (size_t)NEXP * CAP * 4, stream);  // -1 = empty

  // Weight convert+transpose (independent of routing).
  transpose_cvt_kernel<<<dim3(DFF / 32, D / 32, NEXP), 256, 0, stream>>>(
      cfc, cfc_t, D, DFF);
  transpose_cvt_kernel<<<dim3(D / 32, DFF / 32, NEXP), 256, 0, stream>>>(
      cproj, cproj_t, DFF, D);

  router_kernel<<<T_TOK / 4, 256, 0, stream>>>(x, wg, top_e, top_p);
  rank_kernel<<<1, 1024, 0, stream>>>(top_e, top_p, slot_token, tok_slot, tok_w);
  gather_cvt_kernel<<<NEXP * CAP, 256, 0, stream>>>(x, slot_token, xb);

  // Expert MLP: h = gelu(xb @ cfc), eo = h @ cproj   (bf16 MFMA)
  gemm_mfma_kernel<true, true><<<dim3(DFF / 128, CAP / 128, NEXP), 256, 0, stream>>>(
      xb, cfc_t, h, CAP, DFF, D);
  gemm_mfma_kernel<false, false><<<dim3(D / 128, CAP / 128, NEXP), 256, 0, stream>>>(
      h, cproj_t, eo, CAP, D, DFF);

  combine_kernel<<<T_TOK, 256, 0, stream>>>(eo, tok_slot, tok_w, out);
}

// Round 3
// 634.009 us; speedup vs baseline: 4.0193x; 1.0581x over previous
//
#include <hip/hip_runtime.h>
#include <hip/hip_bf16.h>
#include <math.h>

// Problem constants (B=4, C=1024, d=1024)
#define T_TOK 4096
#define D     1024
#define DFF   4096
#define NEXP  8
#define CAP   1280   // floor(2*1.25*4096/8)=1280, already even
#define TOPK  2

typedef __bf16 bf16x8 __attribute__((ext_vector_type(8)));
typedef float floatx4 __attribute__((ext_vector_type(4)));

__device__ __forceinline__ unsigned short f2bf(float f) {
  union { float f; unsigned u; } un; un.f = f;
  unsigned r = un.u + 0x7FFF + ((un.u >> 16) & 1);  // RNE
  return (unsigned short)(r >> 16);
}

// ---------------------------------------------------------------------------
// Router (unchanged, verified): top-2, lowest-index tie-break, softmax.
// ---------------------------------------------------------------------------
__global__ __launch_bounds__(256) void router_kernel(
    const float* __restrict__ x, const float* __restrict__ wg,
    int* __restrict__ top_e, float* __restrict__ top_p) {
  int t = blockIdx.x * 4 + (threadIdx.x >> 6);
  int lane = threadIdx.x & 63;
  if (t >= T_TOK) return;
  const float* xr = x + (size_t)t * D;
  float acc[NEXP];
#pragma unroll
  for (int e = 0; e < NEXP; e++) acc[e] = 0.f;
  for (int dd = lane; dd < D; dd += 64) {
    float xv = xr[dd];
    const float* wr = wg + dd * NEXP;
#pragma unroll
    for (int e = 0; e < NEXP; e++) acc[e] += xv * wr[e];
  }
#pragma unroll
  for (int off = 32; off > 0; off >>= 1) {
#pragma unroll
    for (int e = 0; e < NEXP; e++) acc[e] += __shfl_xor(acc[e], off, 64);
  }
  if (lane == 0) {
    int b0 = 0; float v0 = acc[0];
    for (int e = 1; e < NEXP; e++) if (acc[e] > v0) { v0 = acc[e]; b0 = e; }
    int b1 = -1; float v1 = -INFINITY;
    for (int e = 0; e < NEXP; e++) if (e != b0 && acc[e] > v1) { v1 = acc[e]; b1 = e; }
    float e1 = expf(v1 - v0);
    float s = 1.0f + e1;
    top_e[t * 2 + 0] = b0; top_e[t * 2 + 1] = b1;
    top_p[t * 2 + 0] = 1.0f / s; top_p[t * 2 + 1] = e1 / s;
  }
}

// ---------------------------------------------------------------------------
// Rank/capacity: same nanoMoE cumsum semantics as verified round-1 kernel,
// but scan via wave shuffles (6 barriers total instead of 40). Also clears
// slot_token (replaces the memsetAsync dispatch).
// ---------------------------------------------------------------------------
__global__ __launch_bounds__(1024) void rank_kernel(
    const int* __restrict__ top_e, const float* __restrict__ top_p,
    int* __restrict__ slot_token, int* __restrict__ tok_slot,
    float* __restrict__ tok_w) {
  __shared__ int wsum[16][NEXP];
  __shared__ int wscan[16][NEXP];
  int tid = threadIdx.x;
  int lane = tid & 63, w = tid >> 6;

  for (int s = tid; s < NEXP * CAP; s += 1024) slot_token[s] = -1;
  __syncthreads();  // clear visible before any assignment writes

  int base[NEXP];
#pragma unroll
  for (int e = 0; e < NEXP; e++) base[e] = 0;

  for (int k = 0; k < TOPK; k++) {
    int cnt[NEXP];
#pragma unroll
    for (int e = 0; e < NEXP; e++) cnt[e] = 0;
    int eloc[4];
#pragma unroll
    for (int i = 0; i < 4; i++) {
      int t = tid * 4 + i;
      int e = top_e[t * 2 + k];
      eloc[i] = e;
#pragma unroll
      for (int q = 0; q < NEXP; q++) cnt[q] += (q == e);
    }
    // intra-wave inclusive scan (8-wide vector), no barriers
    int inc[NEXP];
#pragma unroll
    for (int e = 0; e < NEXP; e++) inc[e] = cnt[e];
    for (int off = 1; off < 64; off <<= 1) {
#pragma unroll
      for (int e = 0; e < NEXP; e++) {
        int v = __shfl_up(inc[e], off, 64);
        if (lane >= off) inc[e] += v;
      }
    }
    if (lane == 63)
#pragma unroll
      for (int e = 0; e < NEXP; e++) wsum[w][e] = inc[e];
    __syncthreads();
    if (w == 0 && lane < 16) {
      int s[NEXP];
#pragma unroll
      for (int e = 0; e < NEXP; e++) s[e] = wsum[lane][e];
      for (int off = 1; off < 16; off <<= 1) {
#pragma unroll
        for (int e = 0; e < NEXP; e++) {
          int v = __shfl_up(s[e], off, 64);
          if (lane >= off) s[e] += v;
        }
      }
#pragma unroll
      for (int e = 0; e < NEXP; e++) wscan[lane][e] = s[e];
    }
    __syncthreads();
    int excl[NEXP];
#pragma unroll
    for (int e = 0; e < NEXP; e++)
      excl[e] = inc[e] - cnt[e] + (w ? wscan[w - 1][e] : 0) + base[e];

    int run[NEXP];
#pragma unroll
    for (int e = 0; e < NEXP; e++) run[e] = 0;
#pragma unroll
    for (int i = 0; i < 4; i++) {
      int t = tid * 4 + i;
      int e = eloc[i];
      int r = 0;
#pragma unroll
      for (int q = 0; q < NEXP; q++)
        if (q == e) { r = excl[q] + run[q]; run[q]++; }
      if (r < CAP) {
        slot_token[e * CAP + r] = t;
        tok_slot[t * 2 + k] = e * CAP + r;
      } else {
        tok_slot[t * 2 + k] = -1;
      }
      tok_w[t * 2 + k] = top_p[t * 2 + k];
    }
#pragma unroll
    for (int e = 0; e < NEXP; e++) base[e] += wscan[15][e];
    __syncthreads();  // protect wsum/wscan reuse next k
  }
}

// ---------------------------------------------------------------------------
// Gather + fp32->bf16 (unchanged, verified).
// ---------------------------------------------------------------------------
__global__ __launch_bounds__(256) void gather_cvt_kernel(
    const float* __restrict__ x, const int* __restrict__ slot_token,
    unsigned short* __restrict__ xb) {
  int slot = blockIdx.x;
  int tok = slot_token[slot];
  int i = threadIdx.x;
  float4 v = make_float4(0.f, 0.f, 0.f, 0.f);
  if (tok >= 0) v = ((const float4*)(x + (size_t)tok * D))[i];
  ushort4 o;
  o.x = f2bf(v.x); o.y = f2bf(v.y); o.z = f2bf(v.z); o.w = f2bf(v.w);
  ((ushort4*)(xb + (size_t)slot * D))[i] = o;
}

// ---------------------------------------------------------------------------
// Transpose + fp32->bf16, 64x64 tile: float4 global loads, ushort4 stores.
// src [E][R][Cc] fp32 -> dst [E][Cc][R] bf16.
// ---------------------------------------------------------------------------
__global__ __launch_bounds__(256) void transpose_cvt_kernel(
    const float* __restrict__ src, unsigned short* __restrict__ dst,
    int R, int Cc) {
  __shared__ float tile[64][65];
  int e = blockIdx.z;
  src += (size_t)e * R * Cc;
  dst += (size_t)e * R * Cc;
  int r0 = blockIdx.y * 64, c0 = blockIdx.x * 64;
  int tr = threadIdx.x >> 4;         // 0..15
  int tc = (threadIdx.x & 15) * 4;   // 0..60
#pragma unroll
  for (int i = 0; i < 64; i += 16) {
    float4 v = *(const float4*)(src + (size_t)(r0 + tr + i) * Cc + c0 + tc);
    tile[tr + i][tc + 0] = v.x;
    tile[tr + i][tc + 1] = v.y;
    tile[tr + i][tc + 2] = v.z;
    tile[tr + i][tc + 3] = v.w;
  }
  __syncthreads();
#pragma unroll
  for (int i = 0; i < 64; i += 16) {
    int c = tr + i, r = tc;
    ushort4 o;
    o.x = f2bf(tile[r + 0][c]);
    o.y = f2bf(tile[r + 1][c]);
    o.z = f2bf(tile[r + 2][c]);
    o.w = f2bf(tile[r + 3][c]);
    *(ushort4*)(dst + (size_t)(c0 + c) * R + r0 + r) = o;
  }
}

// ---------------------------------------------------------------------------
// bf16 MFMA GEMM, 512 threads = 8 waves (4x2), wave tile 32x64, block 128x128.
// MODE 0: h = gelu(xb @ cfc_t^T), K=1024, grid (e, y, x) -> XCD=e pinning.
// MODE 1: eo_half = h @ cproj_t^T, split-K x2 (disjoint outputs), K-half=2048,
//         grid (x, y, e*2+kh) -> XCD=x (measured best for this shape).
// ---------------------------------------------------------------------------
template <int MODE>
__global__ __launch_bounds__(512) void gemm_mfma_kernel(
    const unsigned short* __restrict__ A,
    const unsigned short* __restrict__ Bt,
    void* __restrict__ Cv) {
  constexpr int MM = CAP;
  constexpr int NN = (MODE == 0) ? DFF : D;
  constexpr int LDA = (MODE == 0) ? D : DFF;      // row stride of A and Bt
  constexpr int KLEN = (MODE == 0) ? D : DFF / 2; // K per block

  __shared__ unsigned short As[128 * 32];  // [m][k] 8 KB
  __shared__ unsigned short Bs[128 * 32];  // [n][k] 8 KB

  int e, yt, xt, kh;
  if (MODE == 0) {
    e = blockIdx.x; yt = blockIdx.y; xt = blockIdx.z; kh = 0;
  } else {
    xt = blockIdx.x; yt = blockIdx.y; e = blockIdx.z >> 1; kh = blockIdx.z & 1;
  }

  const unsigned short* Ae = A + (size_t)e * MM * LDA + (size_t)kh * KLEN;
  const unsigned short* Be = Bt + (size_t)e * NN * LDA + (size_t)kh * KLEN;

  int row0 = yt * 128, col0 = xt * 128;
  int tid = threadIdx.x;
  int wave = tid >> 6, lane = tid & 63;

  // Staging: thread t stages 16 B: row = t>>2 (0..127), k = (t&3)*8.
  // LDS dst = t*16 B: wave-uniform base + lane*16 within each wave.
  size_t a_off = (size_t)(row0 + (tid >> 2)) * LDA + (tid & 3) * 8;
  size_t b_off = (size_t)(col0 + (tid >> 2)) * LDA + (tid & 3) * 8;
  unsigned short* as_dst = As + tid * 8;
  unsigned short* bs_dst = Bs + tid * 8;

  int wm = (wave >> 1) * 32;  // 0,32,64,96
  int wn = (wave & 1) * 64;   // 0,64
  int fr = lane & 15, fq = lane >> 4;

  floatx4 acc[2][4];
#pragma unroll
  for (int i = 0; i < 2; i++)
#pragma unroll
    for (int j = 0; j < 4; j++) acc[i][j] = (floatx4){0.f, 0.f, 0.f, 0.f};

  for (int k0 = 0; k0 < KLEN; k0 += 32) {
    __builtin_amdgcn_global_load_lds(
        (const __attribute__((address_space(1))) unsigned int*)(Ae + a_off + k0),
        (__attribute__((address_space(3))) unsigned int*)as_dst, 16, 0, 0);
    __builtin_amdgcn_global_load_lds(
        (const __attribute__((address_space(1))) unsigned int*)(Be + b_off + k0),
        (__attribute__((address_space(3))) unsigned int*)bs_dst, 16, 0, 0);
    __syncthreads();

    bf16x8 af[2], bfr[4];
#pragma unroll
    for (int mi = 0; mi < 2; mi++)
      af[mi] = *(const bf16x8*)&As[(wm + mi * 16 + fr) * 32 + fq * 8];
#pragma unroll
    for (int ni = 0; ni < 4; ni++)
      bfr[ni] = *(const bf16x8*)&Bs[(wn + ni * 16 + fr) * 32 + fq * 8];
#pragma unroll
    for (int mi = 0; mi < 2; mi++)
#pragma unroll
      for (int ni = 0; ni < 4; ni++)
        acc[mi][ni] = __builtin_amdgcn_mfma_f32_16x16x32_bf16(
            af[mi], bfr[ni], acc[mi][ni], 0, 0, 0);
    __syncthreads();
  }

  // Epilogue. C/D layout: col = lane&15, row = (lane>>4)*4 + reg.
  int orow0 = row0 + wm + fq * 4;
  int ocol0 = col0 + wn + fr;
  if (MODE == 0) {
    unsigned short* Cb = (unsigned short*)Cv + (size_t)e * MM * NN;
#pragma unroll
    for (int mi = 0; mi < 2; mi++)
#pragma unroll
      for (int ni = 0; ni < 4; ni++)
#pragma unroll
        for (int r = 0; r < 4; r++) {
          float v = acc[mi][ni][r];
          v = 0.5f * v * (1.f + erff(v * 0.70710678118654752f));
          Cb[(size_t)(orow0 + mi * 16 + r) * NN + (ocol0 + ni * 16)] = f2bf(v);
        }
  } else {
    float* Cf = (float*)Cv + ((size_t)kh * NEXP + e) * MM * NN;
#pragma unroll
    for (int mi = 0; mi < 2; mi++)
#pragma unroll
      for (int ni = 0; ni < 4; ni++)
#pragma unroll
        for (int r = 0; r < 4; r++)
          Cf[(size_t)(orow0 + mi * 16 + r) * NN + (ocol0 + ni * 16)] =
              acc[mi][ni][r];
  }
}

// ---------------------------------------------------------------------------
// Combine: out[t,:] = sum_k kept(w_k * (eo0[slot_k,:] + eo1[slot_k,:])).
// ---------------------------------------------------------------------------
__global__ __launch_bounds__(256) void combine_kernel(
    const float* __restrict__ eo, const int* __restrict__ tok_slot,
    const float* __restrict__ tok_w, float* __restrict__ out) {
  int t = blockIdx.x;
  int i = threadIdx.x;
  const size_t half = (size_t)NEXP * CAP * D;
  float4 acc = make_float4(0.f, 0.f, 0.f, 0.f);
#pragma unroll
  for (int k = 0; k < TOPK; k++) {
    int s = tok_slot[t * 2 + k];
    if (s >= 0) {
      float w = tok_w[t * 2 + k];
      float4 v0 = ((const float4*)(eo + (size_t)s * D))[i];
      float4 v1 = ((const float4*)(eo + half + (size_t)s * D))[i];
      acc.x += w * (v0.x + v1.x);
      acc.y += w * (v0.y + v1.y);
      acc.z += w * (v0.z + v1.z);
      acc.w += w * (v0.w + v1.w);
    }
  }
  ((float4*)(out + (size_t)t * D))[i] = acc;
}

// ---------------------------------------------------------------------------
extern "C" void kernel_launch(void* const* d_in, const int* in_sizes, int n_in,
                              void* d_out, int out_size, void* d_ws, size_t ws_size,
                              hipStream_t stream) {
  const float* x     = (const float*)d_in[0];  // [4,1024,1024]
  const float* wg    = (const float*)d_in[1];  // [1024,8]
  const float* cfc   = (const float*)d_in[2];  // [8,1024,4096]
  const float* cproj = (const float*)d_in[3];  // [8,4096,1024]
  float* out = (float*)d_out;

  char* ws = (char*)d_ws;
  size_t off = 0;
  auto alloc = [&](size_t bytes) -> void* {
    void* p = ws + off;
    off += (bytes + 255) & ~(size_t)255;
    return p;
  };
  int*   top_e      = (int*)  alloc((size_t)T_TOK * 2 * 4);
  float* top_p      = (float*)alloc((size_t)T_TOK * 2 * 4);
  int*   slot_token = (int*)  alloc((size_t)NEXP * CAP * 4);
  int*   tok_slot   = (int*)  alloc((size_t)T_TOK * 2 * 4);
  float* tok_w      = (float*)alloc((size_t)T_TOK * 2 * 4);
  unsigned short* xb      = (unsigned short*)alloc((size_t)NEXP * CAP * D * 2);   // 20 MB
  unsigned short* cfc_t   = (unsigned short*)alloc((size_t)NEXP * D * DFF * 2);   // 67 MB [e][DFF][D]
  unsigned short* cproj_t = (unsigned short*)alloc((size_t)NEXP * DFF * D * 2);   // 67 MB [e][D][DFF]
  unsigned short* h       = (unsigned short*)alloc((size_t)NEXP * CAP * DFF * 2); // 84 MB
  // eo split-K halves: [2][NEXP][CAP][D] fp32 = 84 MB, aliases dead xb+cfc_t (87.9 MB).
  float* eo = (float*)xb;

  // Weight convert+transpose (independent of routing).
  transpose_cvt_kernel<<<dim3(DFF / 64, D / 64, NEXP), 256, 0, stream>>>(
      cfc, cfc_t, D, DFF);
  transpose_cvt_kernel<<<dim3(D / 64, DFF / 64, NEXP), 256, 0, stream>>>(
      cproj, cproj_t, DFF, D);

  router_kernel<<<T_TOK / 4, 256, 0, stream>>>(x, wg, top_e, top_p);
  rank_kernel<<<1, 1024, 0, stream>>>(top_e, top_p, slot_token, tok_slot, tok_w);
  gather_cvt_kernel<<<NEXP * CAP, 256, 0, stream>>>(x, slot_token, xb);

  // GEMM1: h = gelu(xb @ cfc_t^T). Grid (e, y, x): XCD = e (A-panel L2-resident).
  gemm_mfma_kernel<0><<<dim3(NEXP, CAP / 128, DFF / 128), 512, 0, stream>>>(
      xb, cfc_t, h);
  // GEMM2: eo{0,1} = h @ cproj_t^T split-K. Grid (x, y, e*2+kh): XCD = x.
  gemm_mfma_kernel<1><<<dim3(D / 128, CAP / 128, NEXP * 2), 512, 0, stream>>>(
      h, cproj_t, eo);

  combine_kernel<<<T_TOK, 256, 0, stream>>>(eo, tok_slot, tok_w, out);
}